// Round 3
// baseline (455.435 us; speedup 1.0000x reference)
//
#include <hip/hip_runtime.h>
#include <hip/hip_bf16.h>

// DMAQ_QattenMixer on gfx950.
// Math facts (see reference):
//  - softmax over constant logits is uniform -> w_final = 0.25 exactly (fp32),
//    head_entropies = -log(1/16 + 1e-8) (constant), V/A cancels in adv_q.
//  - core: adv_tot[b] = sum_a 0.25*(aq[b,a]-mq[b,a]) * (adv_w[b,a]-1)
//    adv_w[b,a] = sum_k sigmoid(dot(acts[b,:], si_W[k,a,:]) + si_b[k,a]) * kern[k,a]
// GEMM (B=262144, N=64, K=256) via bf16 MFMA 16x16x32; memory-bound (~303 MB).
// R3: (a) ks-loop NOT unrolled (+explicit 1-deep pipeline) to stop compiler
//     hoisting/spills; __launch_bounds__(256,4) pins <=128 VGPR;
//     (b) aq/mq prefetched before K-loop (kills epilogue latency tail);
//     (c) PROBE: kernel launched twice (2nd -> d_ws) so kernel time is
//     measurable from dur_us arithmetic despite fill-dominated top-5.

typedef __attribute__((ext_vector_type(8))) short short8;     // 8 bf16 (4 VGPRs)
typedef __attribute__((ext_vector_type(4))) short short4v;
typedef __attribute__((ext_vector_type(4))) float floatx4;

#define ACT_K 256           // action dim (GEMM K)
#define NOUT 64             // N_KERNEL * N_AGENTS (GEMM N)
#define LDS_PITCH 264       // 256 + 8 shorts pad
#define ROWS_PER_WAVE 32    // m = 0..1
#define ROWS_PER_BLOCK 128  // 4 waves

__device__ __forceinline__ short f2bf(float f) {
  // round-to-nearest-even fp32 -> bf16 (inputs finite)
  union { float f; unsigned u; } v; v.f = f;
  unsigned r = v.u + 0x7FFFu + ((v.u >> 16) & 1u);
  return (short)(r >> 16);
}

__device__ __forceinline__ float sigmoidf_fast(float x) {
  return 1.0f / (1.0f + __expf(-x));
}

__global__ __launch_bounds__(256, 4) void mixer_main(
    const float* __restrict__ acts,     // (B, 256)
    const float* __restrict__ aq,       // (B, 16)
    const float* __restrict__ mq,       // (B, 16)
    const float* __restrict__ siW,      // (4,16,256) row n=k*16+a major
    const float* __restrict__ sib,      // (4,16)
    const float* __restrict__ siKeys,   // (4,)
    const float* __restrict__ siAgents, // (4,16)
    const float* __restrict__ sel,      // (4,64)
    const float* __restrict__ qkeys,    // (4,64)
    float* __restrict__ out,            // (B,) then mag_reg (1) then entropies (4)
    int nrows)
{
  __shared__ __align__(16) short ldsW[NOUT * LDS_PITCH];

  const int t    = threadIdx.x;
  const int lane = t & 63;
  const int wv   = t >> 6;            // wave id 0..3
  const int quad = lane >> 4;         // 0..3
  const int a    = lane & 15;         // agent id / MFMA col / A-row-in-tile
  const long rowBase = (long)blockIdx.x * ROWS_PER_BLOCK + (long)wv * ROWS_PER_WAVE;

  // A-fragment base: A[m = lane&15][k = quad*8 + j]
  const float* aptr = acts + (rowBase + a) * ACT_K + quad * 8;

  // ---- prefetch aq/mq into registers (in flight across W-stage + K-loop) ----
  float aqv[2][4], mqv[2][4];
  #pragma unroll
  for (int m = 0; m < 2; ++m)
    #pragma unroll
    for (int r = 0; r < 4; ++r) {
      long b = rowBase + m * 16 + quad * 4 + r;
      aqv[m][r] = aq[b * 16 + a];
      mqv[m][r] = mq[b * 16 + a];
    }

  // ---- prefetch first A chunk (latency overlapped with W staging) ----
  floatx4 x[2][2];
  #pragma unroll
  for (int m = 0; m < 2; ++m) {
    const float* p = aptr + (long)m * 16 * ACT_K;
    x[m][0] = *(const floatx4*)(p);
    x[m][1] = *(const floatx4*)(p + 4);
  }

  // ---- stage W: 16384 fp32 -> bf16 into padded LDS (once per block) ----
  #pragma unroll 4
  for (int i = 0; i < 16; ++i) {
    int flat = (i * 256 + t) * 4;     // 4096 float4 total
    int n = flat >> 8;                // weight row (0..63)
    int d = flat & 255;               // column
    floatx4 w = *(const floatx4*)(siW + flat);
    short4v s;
    s[0] = f2bf(w.x); s[1] = f2bf(w.y); s[2] = f2bf(w.z); s[3] = f2bf(w.w);
    *(short4v*)(&ldsW[n * LDS_PITCH + d]) = s;   // 8B store, 8B aligned
  }

  floatx4 acc[2][4];   // [mtile][ntile]
  #pragma unroll
  for (int m = 0; m < 2; ++m)
    #pragma unroll
    for (int n = 0; n < 4; ++n)
      acc[m][n] = (floatx4){0.f, 0.f, 0.f, 0.f};

  // B-fragment base in LDS: B[k][col], col = lane&15 -> weight row = n*16 + a
  const short* wbase = ldsW + a * LDS_PITCH + quad * 8;

  __syncthreads();

  // ---- K loop: 8 ksteps of K=32; NOT unrolled (bounded registers), 1-deep
  //      pipeline: convert in-flight x, reissue x for ks+1, then MFMA. ----
  #pragma unroll 1
  for (int ks = 0; ks < 8; ++ks) {
    short8 bf[4];
    #pragma unroll
    for (int n = 0; n < 4; ++n)
      bf[n] = *(const short8*)(wbase + n * 16 * LDS_PITCH + ks * 32);

    short8 af[2];
    #pragma unroll
    for (int m = 0; m < 2; ++m) {
      af[m][0] = f2bf(x[m][0].x); af[m][1] = f2bf(x[m][0].y);
      af[m][2] = f2bf(x[m][0].z); af[m][3] = f2bf(x[m][0].w);
      af[m][4] = f2bf(x[m][1].x); af[m][5] = f2bf(x[m][1].y);
      af[m][6] = f2bf(x[m][1].z); af[m][7] = f2bf(x[m][1].w);
    }
    if (ks < 7) {
      #pragma unroll
      for (int m = 0; m < 2; ++m) {
        const float* p = aptr + (long)m * 16 * ACT_K + (ks + 1) * 32;
        x[m][0] = *(const floatx4*)(p);
        x[m][1] = *(const floatx4*)(p + 4);
      }
    }
    #pragma unroll
    for (int m = 0; m < 2; ++m)
      #pragma unroll
      for (int n = 0; n < 4; ++n)
        acc[m][n] = __builtin_amdgcn_mfma_f32_16x16x32_bf16(af[m], bf[n], acc[m][n], 0, 0, 0);
  }

  // ---- epilogue ----
  // C/D layout: col = lane&15 (=a), row = quad*4 + reg (+m*16).
  // ntile == SI kernel index k (since weight row n = k*16 + a).
  float kern[4], bias[4];
  #pragma unroll
  for (int k = 0; k < 4; ++k) {
    kern[k] = (fabsf(siKeys[k]) + 1e-10f) * sigmoidf_fast(siAgents[k * 16 + a]);
    bias[k] = sib[k * 16 + a];
  }

  #pragma unroll
  for (int m = 0; m < 2; ++m) {
    floatx4 res;
    #pragma unroll
    for (int r = 0; r < 4; ++r) {
      float advw = 0.f;
      #pragma unroll
      for (int k = 0; k < 4; ++k) {
        float xs = sigmoidf_fast(acc[m][k][r] + bias[k]);
        advw += xs * kern[k];
      }
      float c = 0.25f * (aqv[m][r] - mqv[m][r]) * (advw - 1.0f);
      // reduce over agents: masks 8/4/2/1 stay inside each 16-lane group
      c += __shfl_xor(c, 8);
      c += __shfl_xor(c, 4);
      c += __shfl_xor(c, 2);
      c += __shfl_xor(c, 1);
      res[r] = c;
    }
    if (a == 0)
      *(floatx4*)(out + rowBase + m * 16 + quad * 4) = res;  // 4 consecutive rows
  }

  // ---- scalar outputs (folded; one wave of block 0) ----
  if (blockIdx.x == 0 && wv == 0) {
    float s = 0.f;
    #pragma unroll
    for (int h = 0; h < 4; ++h) {
      float p = sel[h * 64 + lane] * qkeys[h * 64 + lane];
      #pragma unroll
      for (int msk = 32; msk; msk >>= 1) p += __shfl_xor(p, msk);
      s += p * p;                      // all lanes hold the head-h logit
    }
    if (lane == 0) out[nrows] = 0.001f * s;                  // attend_mag_regs
    if (lane < 4)  out[nrows + 1 + lane] = -logf(0.0625f + 1e-8f);  // entropies
  }
}

extern "C" void kernel_launch(void* const* d_in, const int* in_sizes, int n_in,
                              void* d_out, int out_size, void* d_ws, size_t ws_size,
                              hipStream_t stream) {
  const float* agent_qs  = (const float*)d_in[0];
  const float* actions   = (const float*)d_in[1];
  const float* max_q_i   = (const float*)d_in[2];
  const float* selectors = (const float*)d_in[3];
  const float* keys      = (const float*)d_in[4];
  // d_in[5] = V : cancels in adv_q, unused
  const float* si_keys   = (const float*)d_in[6];
  const float* si_agents = (const float*)d_in[7];
  const float* si_W      = (const float*)d_in[8];
  const float* si_b      = (const float*)d_in[9];
  float* out = (float*)d_out;

  const int nrows = in_sizes[0] / 16;              // 262144
  const int blocks = nrows / ROWS_PER_BLOCK;       // 2048 (exact)

  // real output
  mixer_main<<<blocks, 256, 0, stream>>>(actions, agent_qs, max_q_i,
                                         si_W, si_b, si_keys, si_agents,
                                         selectors, keys, out, nrows);
  // PROBE launch (same work, writes to scratch): makes kernel time visible as
  // dur_us delta. Remove once kernel time is pinned down.
  mixer_main<<<blocks, 256, 0, stream>>>(actions, agent_qs, max_q_i,
                                         si_W, si_b, si_keys, si_agents,
                                         selectors, keys, (float*)d_ws, nrows);
}

// Round 4
// 399.609 us; speedup vs baseline: 1.1397x; 1.1397x over previous
//
#include <hip/hip_runtime.h>
#include <hip/hip_bf16.h>

// DMAQ_QattenMixer on gfx950.
// Math facts (see reference):
//  - softmax over constant logits is uniform -> w_final = 0.25 exactly (fp32),
//    head_entropies = -log(1/16 + 1e-8) (constant), V/A cancels in adv_q.
//  - core: adv_tot[b] = sum_a 0.25*(aq[b,a]-mq[b,a]) * (adv_w[b,a]-1)
//    adv_w[b,a] = sum_k sigmoid(dot(acts[b,:], si_W[k,a,:]) + si_b[k,a]) * kern[k,a]
// GEMM (B=262144, N=64, K=256) via bf16 MFMA 16x16x32; memory-bound (~303 MB).
// R4 (final): R3 kernel, probe launch removed. Measured (R2 vs R3 delta):
// kernel ~= 55.6 us => 5.45 TB/s effective = 86% of achievable HBM BW
// (harness's own 1 GB fills run at 6.6-6.8 TB/s). dur_us is dominated by
// ~345 us of harness poison-fill/restore traffic outside our control.

typedef __attribute__((ext_vector_type(8))) short short8;     // 8 bf16 (4 VGPRs)
typedef __attribute__((ext_vector_type(4))) short short4v;
typedef __attribute__((ext_vector_type(4))) float floatx4;

#define ACT_K 256           // action dim (GEMM K)
#define NOUT 64             // N_KERNEL * N_AGENTS (GEMM N)
#define LDS_PITCH 264       // 256 + 8 shorts pad
#define ROWS_PER_WAVE 32    // m = 0..1
#define ROWS_PER_BLOCK 128  // 4 waves

__device__ __forceinline__ short f2bf(float f) {
  // round-to-nearest-even fp32 -> bf16 (inputs finite)
  union { float f; unsigned u; } v; v.f = f;
  unsigned r = v.u + 0x7FFFu + ((v.u >> 16) & 1u);
  return (short)(r >> 16);
}

__device__ __forceinline__ float sigmoidf_fast(float x) {
  return 1.0f / (1.0f + __expf(-x));
}

__global__ __launch_bounds__(256, 4) void mixer_main(
    const float* __restrict__ acts,     // (B, 256)
    const float* __restrict__ aq,       // (B, 16)
    const float* __restrict__ mq,       // (B, 16)
    const float* __restrict__ siW,      // (4,16,256) row n=k*16+a major
    const float* __restrict__ sib,      // (4,16)
    const float* __restrict__ siKeys,   // (4,)
    const float* __restrict__ siAgents, // (4,16)
    const float* __restrict__ sel,      // (4,64)
    const float* __restrict__ qkeys,    // (4,64)
    float* __restrict__ out,            // (B,) then mag_reg (1) then entropies (4)
    int nrows)
{
  __shared__ __align__(16) short ldsW[NOUT * LDS_PITCH];

  const int t    = threadIdx.x;
  const int lane = t & 63;
  const int wv   = t >> 6;            // wave id 0..3
  const int quad = lane >> 4;         // 0..3
  const int a    = lane & 15;         // agent id / MFMA col / A-row-in-tile
  const long rowBase = (long)blockIdx.x * ROWS_PER_BLOCK + (long)wv * ROWS_PER_WAVE;

  // A-fragment base: A[m = lane&15][k = quad*8 + j]
  const float* aptr = acts + (rowBase + a) * ACT_K + quad * 8;

  // ---- prefetch aq/mq into registers (in flight across W-stage + K-loop) ----
  float aqv[2][4], mqv[2][4];
  #pragma unroll
  for (int m = 0; m < 2; ++m)
    #pragma unroll
    for (int r = 0; r < 4; ++r) {
      long b = rowBase + m * 16 + quad * 4 + r;
      aqv[m][r] = aq[b * 16 + a];
      mqv[m][r] = mq[b * 16 + a];
    }

  // ---- prefetch first A chunk (latency overlapped with W staging) ----
  floatx4 x[2][2];
  #pragma unroll
  for (int m = 0; m < 2; ++m) {
    const float* p = aptr + (long)m * 16 * ACT_K;
    x[m][0] = *(const floatx4*)(p);
    x[m][1] = *(const floatx4*)(p + 4);
  }

  // ---- stage W: 16384 fp32 -> bf16 into padded LDS (once per block) ----
  #pragma unroll 4
  for (int i = 0; i < 16; ++i) {
    int flat = (i * 256 + t) * 4;     // 4096 float4 total
    int n = flat >> 8;                // weight row (0..63)
    int d = flat & 255;               // column
    floatx4 w = *(const floatx4*)(siW + flat);
    short4v s;
    s[0] = f2bf(w.x); s[1] = f2bf(w.y); s[2] = f2bf(w.z); s[3] = f2bf(w.w);
    *(short4v*)(&ldsW[n * LDS_PITCH + d]) = s;   // 8B store, 8B aligned
  }

  floatx4 acc[2][4];   // [mtile][ntile]
  #pragma unroll
  for (int m = 0; m < 2; ++m)
    #pragma unroll
    for (int n = 0; n < 4; ++n)
      acc[m][n] = (floatx4){0.f, 0.f, 0.f, 0.f};

  // B-fragment base in LDS: B[k][col], col = lane&15 -> weight row = n*16 + a
  const short* wbase = ldsW + a * LDS_PITCH + quad * 8;

  __syncthreads();

  // ---- K loop: 8 ksteps of K=32; NOT unrolled (bounded registers), 1-deep
  //      pipeline: convert in-flight x, reissue x for ks+1, then MFMA. ----
  #pragma unroll 1
  for (int ks = 0; ks < 8; ++ks) {
    short8 bf[4];
    #pragma unroll
    for (int n = 0; n < 4; ++n)
      bf[n] = *(const short8*)(wbase + n * 16 * LDS_PITCH + ks * 32);

    short8 af[2];
    #pragma unroll
    for (int m = 0; m < 2; ++m) {
      af[m][0] = f2bf(x[m][0].x); af[m][1] = f2bf(x[m][0].y);
      af[m][2] = f2bf(x[m][0].z); af[m][3] = f2bf(x[m][0].w);
      af[m][4] = f2bf(x[m][1].x); af[m][5] = f2bf(x[m][1].y);
      af[m][6] = f2bf(x[m][1].z); af[m][7] = f2bf(x[m][1].w);
    }
    if (ks < 7) {
      #pragma unroll
      for (int m = 0; m < 2; ++m) {
        const float* p = aptr + (long)m * 16 * ACT_K + (ks + 1) * 32;
        x[m][0] = *(const floatx4*)(p);
        x[m][1] = *(const floatx4*)(p + 4);
      }
    }
    #pragma unroll
    for (int m = 0; m < 2; ++m)
      #pragma unroll
      for (int n = 0; n < 4; ++n)
        acc[m][n] = __builtin_amdgcn_mfma_f32_16x16x32_bf16(af[m], bf[n], acc[m][n], 0, 0, 0);
  }

  // ---- epilogue ----
  // C/D layout: col = lane&15 (=a), row = quad*4 + reg (+m*16).
  // ntile == SI kernel index k (since weight row n = k*16 + a).
  float kern[4], bias[4];
  #pragma unroll
  for (int k = 0; k < 4; ++k) {
    kern[k] = (fabsf(siKeys[k]) + 1e-10f) * sigmoidf_fast(siAgents[k * 16 + a]);
    bias[k] = sib[k * 16 + a];
  }

  #pragma unroll
  for (int m = 0; m < 2; ++m) {
    floatx4 res;
    #pragma unroll
    for (int r = 0; r < 4; ++r) {
      float advw = 0.f;
      #pragma unroll
      for (int k = 0; k < 4; ++k) {
        float xs = sigmoidf_fast(acc[m][k][r] + bias[k]);
        advw += xs * kern[k];
      }
      float c = 0.25f * (aqv[m][r] - mqv[m][r]) * (advw - 1.0f);
      // reduce over agents: masks 8/4/2/1 stay inside each 16-lane group
      c += __shfl_xor(c, 8);
      c += __shfl_xor(c, 4);
      c += __shfl_xor(c, 2);
      c += __shfl_xor(c, 1);
      res[r] = c;
    }
    if (a == 0)
      *(floatx4*)(out + rowBase + m * 16 + quad * 4) = res;  // 4 consecutive rows
  }

  // ---- scalar outputs (folded; one wave of block 0) ----
  if (blockIdx.x == 0 && wv == 0) {
    float s = 0.f;
    #pragma unroll
    for (int h = 0; h < 4; ++h) {
      float p = sel[h * 64 + lane] * qkeys[h * 64 + lane];
      #pragma unroll
      for (int msk = 32; msk; msk >>= 1) p += __shfl_xor(p, msk);
      s += p * p;                      // all lanes hold the head-h logit
    }
    if (lane == 0) out[nrows] = 0.001f * s;                  // attend_mag_regs
    if (lane < 4)  out[nrows + 1 + lane] = -logf(0.0625f + 1e-8f);  // entropies
  }
}

extern "C" void kernel_launch(void* const* d_in, const int* in_sizes, int n_in,
                              void* d_out, int out_size, void* d_ws, size_t ws_size,
                              hipStream_t stream) {
  const float* agent_qs  = (const float*)d_in[0];
  const float* actions   = (const float*)d_in[1];
  const float* max_q_i   = (const float*)d_in[2];
  const float* selectors = (const float*)d_in[3];
  const float* keys      = (const float*)d_in[4];
  // d_in[5] = V : cancels in adv_q, unused
  const float* si_keys   = (const float*)d_in[6];
  const float* si_agents = (const float*)d_in[7];
  const float* si_W      = (const float*)d_in[8];
  const float* si_b      = (const float*)d_in[9];
  float* out = (float*)d_out;

  const int nrows = in_sizes[0] / 16;              // 262144
  const int blocks = nrows / ROWS_PER_BLOCK;       // 2048 (exact)

  mixer_main<<<blocks, 256, 0, stream>>>(actions, agent_qs, max_q_i,
                                         si_W, si_b, si_keys, si_agents,
                                         selectors, keys, out, nrows);
}